// Round 10
// baseline (85.634 us; speedup 1.0000x reference)
//
#include <hip/hip_runtime.h>
#include <hip/hip_fp16.h>
#include <cstdint>

#define B_SZ   1024
#define N_IN   256
#define NLAY   8
#define M_SZ   4096
#define K_SZ   16
// Max column ever READ is 257 + 7*4096 - 1 = 28928; layer-7 out goes to global.
#define NCOLS_LDS 28932
#define SCALE  4.9f
#define TPB    1024

// -SCALE * log2(e): sigmoid(SCALE*a) = 1 / (1 + 2^(-SCALE*log2e*a))
#define NEG_SCALE_LOG2E  (-7.069205700355921f)

// ---------------------------------------------------------------------------
// Prologue: pack (idx, fp16(W)) into one u32 (idx low16, w high16).
// ---------------------------------------------------------------------------
__global__ void pack_kernel(const int* __restrict__ edge_idx,
                            const float* __restrict__ W,
                            uint32_t* __restrict__ packed, int n) {
    int i = blockIdx.x * blockDim.x + threadIdx.x;
    if (i < n) {
        uint32_t id = (uint32_t)edge_idx[i] & 0xFFFFu;
        __half h = __float2half_rn(W[i]);
        packed[i] = id | ((uint32_t)__half_as_ushort(h) << 16);
    }
}

// ---------------------------------------------------------------------------
// Main kernel: one block = 2 batch rows; activation history as half2 in LDS
// (115,728 B; lo = row b0, hi = row b0+1). 1 block/CU (LDS-capped), 16 waves.
//
// R10 structure: 2-deep REGISTER double-buffer on the LDS GATHERS.
// Within a layer, all 4 m-iterations read a frozen vals region (layer-l
// writes land in columns not read until after the barrier), so iter i+1's
// 16 ds_reads are issued BEFORE consuming iter i. Each wave then waits
// lgkmcnt(15) instead of draining to 0, and the LDS pipe sees a continuous
// stream instead of burst/drain cycles. R5-R9 showed time is invariant
// (77 us) to VALU work, global prefetch and sum-of-conflicts: the serial
// issue->drain->consume chain per wave is the hypothesized critical path.
//
// Packed words pk[i] stay live through consume (v_fma_mix reads the f16
// weight from the high half), so next-layer global prefetch G(l+1,i) is
// placed AFTER consume C(i) - still ~3 iterations of latency cover.
// ---------------------------------------------------------------------------
template <bool PACKED>
__global__ __launch_bounds__(TPB, 4)
void ffn_kernel(const float* __restrict__ x,
                const uint32_t* __restrict__ packed,
                const int* __restrict__ edge_idx,
                const float* __restrict__ W,
                float* __restrict__ out) {
    __shared__ uint32_t vals[NCOLS_LDS];

    const int tid = threadIdx.x;
    const int b0  = blockIdx.x * 2;
    const float* __restrict__ x0 = x + (size_t)b0 * N_IN;
    const float* __restrict__ x1 = x0 + N_IN;
    const int base = N_IN + 1;

    if (PACKED) {
        // Load packed words for (layer l, sub-iter i) into 16 regs.
        auto ldpk = [&](uint32_t dst[16], int l, int i) {
            const int m = tid + i * TPB;
            const uint4* p4 =
                reinterpret_cast<const uint4*>(packed + ((size_t)l * M_SZ + m) * K_SZ);
            #pragma unroll
            for (int j = 0; j < 4; ++j) {
                uint4 v = p4[j];
                dst[4*j+0] = v.x; dst[4*j+1] = v.y; dst[4*j+2] = v.z; dst[4*j+3] = v.w;
            }
        };

        uint32_t pk[4][16];   // packed words, all 4 iters of current layer
        uint32_t gv[2][16];   // gathered vals, 2-deep ping-pong

        // Issue layer-0 packed loads first; x-staging hides their latency.
        #pragma unroll
        for (int i = 0; i < 4; ++i) ldpk(pk[i], 0, i);

        for (int j = tid; j <= N_IN; j += TPB) {
            float v0 = (j < N_IN) ? x0[j] : 1.0f;
            float v1 = (j < N_IN) ? x1[j] : 1.0f;
            __half2 h2 = __floats2half2_rn(v0, v1);
            vals[j] = *reinterpret_cast<uint32_t*>(&h2);
        }
        __syncthreads();

        for (int l = 0; l < NLAY; ++l) {
            // D(0): first iteration's gathers.
            #pragma unroll
            for (int q = 0; q < 16; ++q)
                gv[0][q] = vals[pk[0][q] & 0xFFFFu];

            #pragma unroll
            for (int i = 0; i < 4; ++i) {
                // D(i+1): issue next iteration's gathers before consuming i.
                if (i < 3) {
                    #pragma unroll
                    for (int q = 0; q < 16; ++q)
                        gv[(i + 1) & 1][q] = vals[pk[i + 1][q] & 0xFFFFu];
                }

                // C(i): consume.
                const int m = tid + i * TPB;
                float acc0 = 0.f, acc1 = 0.f;
                #pragma unroll
                for (int q = 0; q < 16; ++q) {
                    uint32_t p = pk[i][q];
                    uint32_t v = gv[i & 1][q];
                    __half2 vh = *reinterpret_cast<__half2*>(&v);
                    __half2 ph = *reinterpret_cast<__half2*>(&p);
                    float wf = __high2float(ph);
                    acc0 = fmaf(__low2float(vh),  wf, acc0);
                    acc1 = fmaf(__high2float(vh), wf, acc1);
                }

                float e0 = __builtin_amdgcn_exp2f(NEG_SCALE_LOG2E * acc0);
                float e1 = __builtin_amdgcn_exp2f(NEG_SCALE_LOG2E * acc1);
                float s0 = __builtin_amdgcn_rcpf(1.0f + e0);
                float s1 = __builtin_amdgcn_rcpf(1.0f + e1);

                if (l < NLAY - 1) {
                    __half2 h2 = __floats2half2_rn(s0, s1);
                    vals[base + l * M_SZ + m] = *reinterpret_cast<uint32_t*>(&h2);
                } else {
                    out[(size_t)b0 * M_SZ + m]       = s0;
                    out[(size_t)(b0 + 1) * M_SZ + m] = s1;
                }

                // G(l+1, i): pk[i] is dead after C(i); refill for next layer.
                // Register-only global load, safe across the coming barrier.
                if (l < NLAY - 1) ldpk(pk[i], l + 1, i);
            }
            __syncthreads();
        }
    } else {
        for (int j = tid; j <= N_IN; j += TPB) {
            float v0 = (j < N_IN) ? x0[j] : 1.0f;
            float v1 = (j < N_IN) ? x1[j] : 1.0f;
            __half2 h2 = __floats2half2_rn(v0, v1);
            vals[j] = *reinterpret_cast<uint32_t*>(&h2);
        }
        __syncthreads();
        for (int l = 0; l < NLAY; ++l) {
            for (int i = 0; i < M_SZ / TPB; ++i) {
                const int m = tid + i * TPB;
                float acc0 = 0.f, acc1 = 0.f;
                const int4*   i4 = reinterpret_cast<const int4*>(edge_idx + ((size_t)l * M_SZ + m) * K_SZ);
                const float4* w4 = reinterpret_cast<const float4*>(W + ((size_t)l * M_SZ + m) * K_SZ);
                #pragma unroll
                for (int j = 0; j < 4; ++j) {
                    int4   ii = i4[j];
                    float4 ww = w4[j];
                    int   idxs[4] = {ii.x, ii.y, ii.z, ii.w};
                    float wts[4]  = {ww.x, ww.y, ww.z, ww.w};
                    #pragma unroll
                    for (int q = 0; q < 4; ++q) {
                        uint32_t v = vals[idxs[q]];
                        __half2 h2 = *reinterpret_cast<__half2*>(&v);
                        acc0 = fmaf(__low2float(h2),  wts[q], acc0);
                        acc1 = fmaf(__high2float(h2), wts[q], acc1);
                    }
                }
                float e0 = __builtin_amdgcn_exp2f(NEG_SCALE_LOG2E * acc0);
                float e1 = __builtin_amdgcn_exp2f(NEG_SCALE_LOG2E * acc1);
                float s0 = __builtin_amdgcn_rcpf(1.0f + e0);
                float s1 = __builtin_amdgcn_rcpf(1.0f + e1);
                if (l < NLAY - 1) {
                    __half2 h2 = __floats2half2_rn(s0, s1);
                    vals[base + l * M_SZ + m] = *reinterpret_cast<uint32_t*>(&h2);
                } else {
                    out[(size_t)b0 * M_SZ + m]       = s0;
                    out[(size_t)(b0 + 1) * M_SZ + m] = s1;
                }
            }
            __syncthreads();
        }
    }
}

extern "C" void kernel_launch(void* const* d_in, const int* in_sizes, int n_in,
                              void* d_out, int out_size, void* d_ws, size_t ws_size,
                              hipStream_t stream) {
    const float* x        = (const float*)d_in[0];
    const float* W        = (const float*)d_in[1];
    const int*   edge_idx = (const int*)d_in[2];
    float*       out      = (float*)d_out;

    const int n = NLAY * M_SZ * K_SZ;  // 524288 packed words = 2 MB
    if (ws_size >= (size_t)n * sizeof(uint32_t)) {
        uint32_t* packed = (uint32_t*)d_ws;
        pack_kernel<<<(n + 255) / 256, 256, 0, stream>>>(edge_idx, W, packed, n);
        ffn_kernel<true><<<B_SZ / 2, TPB, 0, stream>>>(x, packed, nullptr, nullptr, out);
    } else {
        ffn_kernel<false><<<B_SZ / 2, TPB, 0, stream>>>(x, nullptr, edge_idx, W, out);
    }
}